// Round 3
// baseline (436.036 us; speedup 1.0000x reference)
//
#include <hip/hip_runtime.h>

// GAT_gate: B=16, N=1024, D=128. ALL inputs/outputs are FP32 (per reference).
// Internally: bf16 MFMA with fp32 accumulate; softmax/gates/epilogue in fp32.
//
//  K0: WwB = bf16(Ww); W2T[l,f] = bf16(sum_d A[d,l]*Ww[d,f]); wbA[l] = Wb@A (fp32)
//  K1: h = x@Ww^T + Wb ; u = x@W2T^T + wbA  (MFMA) -> h,u bf16 row-major,
//      hT bf16 [b][d][n] via LDS transpose (PV B-fragments for K3)
//  K2: colsum[j] = sum_i (adj[i,j]>0 ? exp(e[i,j]) : 1), rl0 = 1/colsum (fp32)
//      (max-free softmax; e clamped to +-60; exp(60)=1.1e26 << fp32 max)
//  K3: fused: recompute e tile transposed (C-layout col == output row i),
//      att = adj ? exp(e)*rl0[j] : 0 (bf16), shfl-transpose C->A layout,
//      h' = relu(att @ h) via MFMA vs hT, LSTM-gate epilogue, fp32 out.
//
// ws: WwB 32KB | W2T 32KB | wbA 512B | rl0 64KB | h 4MB | u 4MB | hT 4MB (~12.2MB)

#define B_ 16
#define N_ 1024
#define D_ 128

typedef __attribute__((ext_vector_type(8))) short bf16x8;
typedef __attribute__((ext_vector_type(4))) float f32x4;

__device__ __forceinline__ float b2f(unsigned short u) {
    union { unsigned int i; float f; } v; v.i = ((unsigned int)u) << 16; return v.f;
}
__device__ __forceinline__ unsigned short f2b(float f) {
    union { float f; unsigned int i; } v; v.f = f;
    unsigned int x = v.i;
    return (unsigned short)((x + 0x7fffu + ((x >> 16) & 1u)) >> 16);
}
__device__ __forceinline__ float clamp60(float v) {
    return fminf(fmaxf(v, -60.f), 60.f);
}
// load 8 consecutive fp32 and convert to a bf16x8 fragment
__device__ __forceinline__ bf16x8 load8f(const float* p) {
    float4 a = *reinterpret_cast<const float4*>(p);
    float4 b = *reinterpret_cast<const float4*>(p + 4);
    bf16x8 v;
    v[0] = (short)f2b(a.x); v[1] = (short)f2b(a.y);
    v[2] = (short)f2b(a.z); v[3] = (short)f2b(a.w);
    v[4] = (short)f2b(b.x); v[5] = (short)f2b(b.y);
    v[6] = (short)f2b(b.z); v[7] = (short)f2b(b.w);
    return v;
}

// ---------------- K0: fold weights (fp32 in, bf16 out) ----------------
__global__ __launch_bounds__(256) void k0_w2t(
    const float* __restrict__ Ww, const float* __restrict__ Wb,
    const float* __restrict__ A, unsigned short* __restrict__ WwB,
    unsigned short* __restrict__ W2T, float* __restrict__ wbA) {
    int t = blockIdx.x * 256 + threadIdx.x;   // 0..16383
    int l = t >> 7, f = t & 127;
    float acc = 0.f;
    for (int d = 0; d < 128; ++d)
        acc += A[d * 128 + l] * Ww[d * 128 + f];
    W2T[l * 128 + f] = f2b(acc);
    WwB[t] = f2b(Ww[t]);
    if (blockIdx.x == 0 && threadIdx.x < 128) {
        float s = 0.f;
        for (int d = 0; d < 128; ++d) s += Wb[d] * A[d * 128 + threadIdx.x];
        wbA[threadIdx.x] = s;
    }
}

// ---------------- K1: h, u, hT ----------------
__global__ __launch_bounds__(256) void k1_hu(
    const float* __restrict__ x, const unsigned short* __restrict__ WwB,
    const float* __restrict__ Wb, const unsigned short* __restrict__ W2T,
    const float* __restrict__ wbA,
    unsigned short* __restrict__ h, unsigned short* __restrict__ u,
    unsigned short* __restrict__ hT) {
    __shared__ unsigned short lds[4][16][128];
    int w = threadIdx.x >> 6, lane = threadIdx.x & 63;
    int c = lane & 15, q = lane >> 4;
    int rowbase = blockIdx.x * 64 + w * 16;   // flat row (b*1024+n)
    int b = rowbase >> 10;
    int n0 = rowbase & 1023;

    bf16x8 xa[4];
    const float* xrow = x + (size_t)(rowbase + c) * 128;
#pragma unroll
    for (int ks = 0; ks < 4; ++ks)
        xa[ks] = load8f(xrow + ks * 32 + q * 8);

#pragma unroll
    for (int t = 0; t < 8; ++t) {
        f32x4 acch = {0.f, 0.f, 0.f, 0.f};
        f32x4 accu = {0.f, 0.f, 0.f, 0.f};
        const unsigned short* wwrow = WwB + (t * 16 + c) * 128;
        const unsigned short* w2row = W2T + (t * 16 + c) * 128;
#pragma unroll
        for (int ks = 0; ks < 4; ++ks) {
            bf16x8 bw = *reinterpret_cast<const bf16x8*>(wwrow + ks * 32 + q * 8);
            bf16x8 b2 = *reinterpret_cast<const bf16x8*>(w2row + ks * 32 + q * 8);
            acch = __builtin_amdgcn_mfma_f32_16x16x32_bf16(xa[ks], bw, acch, 0, 0, 0);
            accu = __builtin_amdgcn_mfma_f32_16x16x32_bf16(xa[ks], b2, accu, 0, 0, 0);
        }
        float wb = Wb[t * 16 + c];
        float ub = wbA[t * 16 + c];
#pragma unroll
        for (int r = 0; r < 4; ++r) {
            int row = rowbase + q * 4 + r;
            unsigned short hv = f2b(acch[r] + wb);
            unsigned short uv = f2b(accu[r] + ub);
            h[(size_t)row * 128 + t * 16 + c] = hv;
            u[(size_t)row * 128 + t * 16 + c] = uv;
            lds[w][q * 4 + r][t * 16 + c] = hv;
        }
    }
    __syncthreads();
    unsigned int tl[16], th[16];
#pragma unroll
    for (int n = 0; n < 16; ++n) {
        unsigned int v = *reinterpret_cast<unsigned int*>(&lds[w][n][2 * lane]);
        tl[n] = v & 0xffffu; th[n] = v >> 16;
    }
    unsigned int lo[8], hi[8];
#pragma unroll
    for (int k = 0; k < 8; ++k) {
        lo[k] = tl[2 * k] | (tl[2 * k + 1] << 16);
        hi[k] = th[2 * k] | (th[2 * k + 1] << 16);
    }
    size_t base = ((size_t)(b * 128 + 2 * lane)) * 1024 + n0;
    uint4* d0 = reinterpret_cast<uint4*>(hT + base);
    uint4* d1 = reinterpret_cast<uint4*>(hT + base + 1024);
    d0[0] = make_uint4(lo[0], lo[1], lo[2], lo[3]);
    d0[1] = make_uint4(lo[4], lo[5], lo[6], lo[7]);
    d1[0] = make_uint4(hi[0], hi[1], hi[2], hi[3]);
    d1[1] = make_uint4(hi[4], hi[5], hi[6], hi[7]);
}

// ---------------- K2: column sums for softmax ----------------
__global__ __launch_bounds__(256) void k2_stats(
    const unsigned short* __restrict__ h, const unsigned short* __restrict__ u,
    const float* __restrict__ adj, float* __restrict__ rl0) {
    int w = threadIdx.x >> 6, lane = threadIdx.x & 63;
    int c = lane & 15, q = lane >> 4;
    int b = blockIdx.x >> 4;
    int j0 = ((blockIdx.x & 15) * 4 + w) * 16;   // this wave's 16 columns
    const unsigned short* hb = h + (size_t)b * N_ * D_;
    const unsigned short* ub = u + (size_t)b * N_ * D_;

    bf16x8 Bh[4], Bu[4];
#pragma unroll
    for (int ks = 0; ks < 4; ++ks) {
        Bh[ks] = *reinterpret_cast<const bf16x8*>(hb + (j0 + c) * 128 + ks * 32 + q * 8);
        Bu[ks] = *reinterpret_cast<const bf16x8*>(ub + (j0 + c) * 128 + ks * 32 + q * 8);
    }
    float colsum = 0.f;
    const float* adjb = adj + (size_t)b * N_ * N_;

    for (int it = 0; it < 64; ++it) {
        int i0 = it * 16;
        f32x4 acc = {0.f, 0.f, 0.f, 0.f};
#pragma unroll
        for (int ks = 0; ks < 4; ++ks) {
            bf16x8 au = *reinterpret_cast<const bf16x8*>(ub + (i0 + c) * 128 + ks * 32 + q * 8);
            bf16x8 ah = *reinterpret_cast<const bf16x8*>(hb + (i0 + c) * 128 + ks * 32 + q * 8);
            acc = __builtin_amdgcn_mfma_f32_16x16x32_bf16(au, Bh[ks], acc, 0, 0, 0);
            acc = __builtin_amdgcn_mfma_f32_16x16x32_bf16(ah, Bu[ks], acc, 0, 0, 0);
        }
#pragma unroll
        for (int r = 0; r < 4; ++r) {
            int i = i0 + q * 4 + r;
            float av = adjb[(size_t)i * 1024 + j0 + c];
            colsum += (av > 0.f) ? __expf(clamp60(acc[r])) : 1.0f;
        }
    }
    colsum += __shfl_xor(colsum, 16, 64);
    colsum += __shfl_xor(colsum, 32, 64);
    if (q == 0) rl0[b * 1024 + j0 + c] = 1.0f / colsum;
}

// ---------------- K3: fused scores + aggregation + gates ----------------
__global__ __launch_bounds__(256) void k3_fused(
    const unsigned short* __restrict__ h, const unsigned short* __restrict__ uu,
    const float* __restrict__ adj, const float* __restrict__ rl0,
    const unsigned short* __restrict__ hT, const float* __restrict__ x,
    const float* __restrict__ wi_u, const float* __restrict__ wi_x,
    const float* __restrict__ wf_u, const float* __restrict__ wf_x,
    const float* __restrict__ wo_u, const float* __restrict__ wo_x,
    float* __restrict__ out) {
    int w = threadIdx.x >> 6, lane = threadIdx.x & 63;
    int c = lane & 15, q = lane >> 4;
    int b = blockIdx.x >> 4;
    int i0 = ((blockIdx.x & 15) * 4 + w) * 16;   // this wave's 16 output rows
    const unsigned short* hb = h + (size_t)b * N_ * D_;
    const unsigned short* ub = uu + (size_t)b * N_ * D_;
    const unsigned short* hTb = hT + (size_t)b * 128 * 1024;
    const float* adjrow = adj + ((size_t)(b * 1024 + i0 + c)) * 1024;  // row i0+c
    const float* rl0b = rl0 + b * 1024;

    // score B-fragments: fixed i-side (columns of e^T); lane c <-> row i0+c
    bf16x8 Bh[4], Bu[4];
#pragma unroll
    for (int ks = 0; ks < 4; ++ks) {
        Bh[ks] = *reinterpret_cast<const bf16x8*>(hb + (i0 + c) * 128 + ks * 32 + q * 8);
        Bu[ks] = *reinterpret_cast<const bf16x8*>(ub + (i0 + c) * 128 + ks * 32 + q * 8);
    }

    f32x4 hp[8];
#pragma unroll
    for (int t = 0; t < 8; ++t) hp[t] = (f32x4){0.f, 0.f, 0.f, 0.f};

    for (int jp = 0; jp < 32; ++jp) {
        int j0 = jp * 32;
        unsigned int u00, u01, u10, u11;  // packed att (2 sub-tiles x 2 uints)
#pragma unroll
        for (int s = 0; s < 2; ++s) {
            int js = j0 + s * 16;
            f32x4 acc = {0.f, 0.f, 0.f, 0.f};
#pragma unroll
            for (int ks = 0; ks < 4; ++ks) {
                bf16x8 au = *reinterpret_cast<const bf16x8*>(ub + (js + c) * 128 + ks * 32 + q * 8);
                bf16x8 ah = *reinterpret_cast<const bf16x8*>(hb + (js + c) * 128 + ks * 32 + q * 8);
                acc = __builtin_amdgcn_mfma_f32_16x16x32_bf16(au, Bh[ks], acc, 0, 0, 0);
                acc = __builtin_amdgcn_mfma_f32_16x16x32_bf16(ah, Bu[ks], acc, 0, 0, 0);
            }
            // e^T element: (j = js + q*4 + r, i = i0 + c)
            float4 aj = *reinterpret_cast<const float4*>(adjrow + js + q * 4);
            float4 rv = *reinterpret_cast<const float4*>(rl0b + js + q * 4);
            float a0 = (aj.x > 0.f) ? __expf(clamp60(acc[0])) * rv.x : 0.f;
            float a1 = (aj.y > 0.f) ? __expf(clamp60(acc[1])) * rv.y : 0.f;
            float a2 = (aj.z > 0.f) ? __expf(clamp60(acc[2])) * rv.z : 0.f;
            float a3 = (aj.w > 0.f) ? __expf(clamp60(acc[3])) * rv.w : 0.f;
            unsigned int p0 = (unsigned int)f2b(a0) | ((unsigned int)f2b(a1) << 16);
            unsigned int p1 = (unsigned int)f2b(a2) | ((unsigned int)f2b(a3) << 16);
            if (s == 0) { u00 = p0; u01 = p1; } else { u10 = p0; u11 = p1; }
        }
        // shfl-transpose C-layout -> A-layout (lane q needs j = q*8..q*8+7)
        int la = c + 32 * (q & 1);
        int lb = la + 16;
        unsigned int x0 = __shfl((int)u00, la, 64), x1 = __shfl((int)u01, la, 64);
        unsigned int x2 = __shfl((int)u00, lb, 64), x3 = __shfl((int)u01, lb, 64);
        unsigned int y0 = __shfl((int)u10, la, 64), y1 = __shfl((int)u11, la, 64);
        unsigned int y2 = __shfl((int)u10, lb, 64), y3 = __shfl((int)u11, lb, 64);
        bool hiq = (q >> 1) != 0;
        union { unsigned int ui[4]; bf16x8 v; } att;
        att.ui[0] = hiq ? y0 : x0;
        att.ui[1] = hiq ? y1 : x1;
        att.ui[2] = hiq ? y2 : x2;
        att.ui[3] = hiq ? y3 : x3;
#pragma unroll
        for (int t = 0; t < 8; ++t) {
            bf16x8 bt = *reinterpret_cast<const bf16x8*>(
                hTb + (size_t)(t * 16 + c) * 1024 + j0 + q * 8);
            hp[t] = __builtin_amdgcn_mfma_f32_16x16x32_bf16(att.v, bt, hp[t], 0, 0, 0);
        }
    }

    // epilogue: relu, gates, output. hp[t][r] = h'[i0+q*4+r][t*16+c]
    float xv[8][4];
#pragma unroll
    for (int t = 0; t < 8; ++t)
#pragma unroll
        for (int r = 0; r < 4; ++r) {
            hp[t][r] = fmaxf(hp[t][r], 0.f);
            xv[t][r] = x[(size_t)(b * 1024 + i0 + q * 4 + r) * 128 + t * 16 + c];
        }
    float wiu[8], wix[8], wfu[8], wfx[8], wou[8], wox[8];
#pragma unroll
    for (int t = 0; t < 8; ++t) {
        wiu[t] = wi_u[t * 16 + c]; wix[t] = wi_x[t * 16 + c];
        wfu[t] = wf_u[t * 16 + c]; wfx[t] = wf_x[t * 16 + c];
        wou[t] = wo_u[t * 16 + c]; wox[t] = wo_x[t * 16 + c];
    }
#pragma unroll
    for (int r = 0; r < 4; ++r) {
        float zi = 0.f, zf = 0.f, zo = 0.f;
#pragma unroll
        for (int t = 0; t < 8; ++t) {
            zi += hp[t][r] * wiu[t] + xv[t][r] * wix[t];
            zf += hp[t][r] * wfu[t] + xv[t][r] * wfx[t];
            zo += hp[t][r] * wou[t] + xv[t][r] * wox[t];
        }
        zi += __shfl_xor(zi, 1, 64); zi += __shfl_xor(zi, 2, 64);
        zi += __shfl_xor(zi, 4, 64); zi += __shfl_xor(zi, 8, 64);
        zf += __shfl_xor(zf, 1, 64); zf += __shfl_xor(zf, 2, 64);
        zf += __shfl_xor(zf, 4, 64); zf += __shfl_xor(zf, 8, 64);
        zo += __shfl_xor(zo, 1, 64); zo += __shfl_xor(zo, 2, 64);
        zo += __shfl_xor(zo, 4, 64); zo += __shfl_xor(zo, 8, 64);
        float ic = 1.f / (1.f + __expf(-zi));
        float fc = 1.f / (1.f + __expf(-zf));
        float oc = 1.f / (1.f + __expf(-zo));
#pragma unroll
        for (int t = 0; t < 8; ++t) {
            float zz = ic * hp[t][r] + fc * xv[t][r];
            float th = 1.f - 2.f / (__expf(2.f * zz) + 1.f);
            out[(size_t)(b * 1024 + i0 + q * 4 + r) * 128 + t * 16 + c] = oc * th;
        }
    }
}

extern "C" void kernel_launch(void* const* d_in, const int* in_sizes, int n_in,
                              void* d_out, int out_size, void* d_ws, size_t ws_size,
                              hipStream_t stream) {
    const float* x    = (const float*)d_in[0];
    const float* adj  = (const float*)d_in[1];
    const float* Ww   = (const float*)d_in[2];
    const float* Wb   = (const float*)d_in[3];
    const float* A    = (const float*)d_in[4];
    const float* wi_u = (const float*)d_in[5];
    const float* wi_x = (const float*)d_in[6];
    const float* wf_u = (const float*)d_in[7];
    const float* wf_x = (const float*)d_in[8];
    const float* wo_u = (const float*)d_in[9];
    const float* wo_x = (const float*)d_in[10];
    float* out = (float*)d_out;

    char* ws = (char*)d_ws;
    unsigned short* WwB = (unsigned short*)(ws);                          // 32KB
    unsigned short* W2T = (unsigned short*)(ws + (32u << 10));            // 32KB
    float* wbA          = (float*)(ws + (64u << 10));                     // 512B
    float* rl0          = (float*)(ws + (128u << 10));                    // 64KB
    unsigned short* h   = (unsigned short*)(ws + (1u << 20));             // 4MB
    unsigned short* u   = (unsigned short*)(ws + (5u << 20));             // 4MB
    unsigned short* hT  = (unsigned short*)(ws + (9u << 20));             // 4MB

    k0_w2t<<<64, 256, 0, stream>>>(Ww, Wb, A, WwB, W2T, wbA);
    k1_hu<<<256, 256, 0, stream>>>(x, WwB, Wb, W2T, wbA, h, u, hT);
    k2_stats<<<256, 256, 0, stream>>>(h, u, adj, rl0);
    k3_fused<<<256, 256, 0, stream>>>(h, u, adj, rl0, hT, x,
                                      wi_u, wi_x, wf_u, wf_x, wo_u, wo_x, out);
}

// Round 4
// 316.378 us; speedup vs baseline: 1.3782x; 1.3782x over previous
//
#include <hip/hip_runtime.h>

// GAT_gate: B=16, N=1024, D=128. FP32 I/O; bf16 MFMA internally, fp32 accum.
//
//  K0:   WwB = bf16(Ww); W2T = bf16(A^T Ww); wbA = Wb@A (fp32)
//  kmask: adj (64MB fp32) -> 2MB bitmask packed along j (bit j of word (b,i,j>>6))
//  K1:   h = x@Ww^T + Wb ; u = x@W2T^T + wbA -> h,u bf16 row-major; hT bf16 [b][d][n]
//        grid 1024: one 16-row tile/block, 4 waves split t-loop, LDS transpose.
//  K2:   colsum[j] = sum_i (mask ? exp(e[i,j]) : 1); rl0 = 1/colsum.
//        grid 1024: one 16-col tile/block, 4 waves split i-range, LDS reduce.
//  K3:   recompute e tile transposed, att = mask ? exp(e)*rl0[j] : 0 (bf16),
//        shfl-transpose C->A layout, h' = relu(att@h) vs hT, LSTM-gate epilogue.
//        grid 1024: one 16-row tile/block, 4 waves split j-range, LDS hp-reduce.
//
// ws: WwB 32K | W2T 32K | wbA | rl0 64K | h 4M | u 4M | hT 4M | maskJ 2M (~15MB)

#define B_ 16
#define N_ 1024
#define D_ 128

typedef __attribute__((ext_vector_type(8))) short bf16x8;
typedef __attribute__((ext_vector_type(4))) float f32x4;

__device__ __forceinline__ unsigned short f2b(float f) {
    union { float f; unsigned int i; } v; v.f = f;
    unsigned int x = v.i;
    return (unsigned short)((x + 0x7fffu + ((x >> 16) & 1u)) >> 16);
}
__device__ __forceinline__ float clamp60(float v) {
    return fminf(fmaxf(v, -60.f), 60.f);
}
__device__ __forceinline__ bf16x8 load8f(const float* p) {
    float4 a = *reinterpret_cast<const float4*>(p);
    float4 b = *reinterpret_cast<const float4*>(p + 4);
    bf16x8 v;
    v[0] = (short)f2b(a.x); v[1] = (short)f2b(a.y);
    v[2] = (short)f2b(a.z); v[3] = (short)f2b(a.w);
    v[4] = (short)f2b(b.x); v[5] = (short)f2b(b.y);
    v[6] = (short)f2b(b.z); v[7] = (short)f2b(b.w);
    return v;
}

// ---------------- K0: fold weights (fp32 in, bf16 out) ----------------
__global__ __launch_bounds__(256) void k0_w2t(
    const float* __restrict__ Ww, const float* __restrict__ Wb,
    const float* __restrict__ A, unsigned short* __restrict__ WwB,
    unsigned short* __restrict__ W2T, float* __restrict__ wbA) {
    int t = blockIdx.x * 256 + threadIdx.x;   // 0..16383
    int l = t >> 7, f = t & 127;
    float acc = 0.f;
    for (int d = 0; d < 128; ++d)
        acc += A[d * 128 + l] * Ww[d * 128 + f];
    W2T[l * 128 + f] = f2b(acc);
    WwB[t] = f2b(Ww[t]);
    if (blockIdx.x == 0 && threadIdx.x < 128) {
        float s = 0.f;
        for (int d = 0; d < 128; ++d) s += Wb[d] * A[d * 128 + threadIdx.x];
        wbA[threadIdx.x] = s;
    }
}

// ---------------- kmask: adj -> bitmask (packed along j) ----------------
__global__ __launch_bounds__(256) void kmask(
    const float* __restrict__ adj, unsigned long long* __restrict__ maskJ) {
    int w = threadIdx.x >> 6, lane = threadIdx.x & 63;
    size_t base = ((size_t)blockIdx.x * 4 + w) * 256;   // 256 elements per wave
    unsigned long long w0, w1, w2, w3;
    w0 = __ballot(adj[base + 0 * 64 + lane] > 0.f);
    w1 = __ballot(adj[base + 1 * 64 + lane] > 0.f);
    w2 = __ballot(adj[base + 2 * 64 + lane] > 0.f);
    w3 = __ballot(adj[base + 3 * 64 + lane] > 0.f);
    unsigned long long out = lane == 0 ? w0 : lane == 1 ? w1 : lane == 2 ? w2 : w3;
    if (lane < 4) maskJ[(base >> 6) + lane] = out;
}

// ---------------- K1: h, u, hT (grid 1024, 16 rows/block) ----------------
__global__ __launch_bounds__(256) void k1_hu(
    const float* __restrict__ x, const unsigned short* __restrict__ WwB,
    const float* __restrict__ Wb, const unsigned short* __restrict__ W2T,
    const float* __restrict__ wbA,
    unsigned short* __restrict__ h, unsigned short* __restrict__ u,
    unsigned short* __restrict__ hT) {
    __shared__ unsigned short lds[16][128];
    int w = threadIdx.x >> 6, lane = threadIdx.x & 63;
    int c = lane & 15, q = lane >> 4;
    int rowbase = blockIdx.x * 16;            // flat row (b*1024+n)
    int b = rowbase >> 10;
    int n0 = rowbase & 1023;

    bf16x8 xa[4];
    const float* xrow = x + (size_t)(rowbase + c) * 128;
#pragma unroll
    for (int ks = 0; ks < 4; ++ks)
        xa[ks] = load8f(xrow + ks * 32 + q * 8);

#pragma unroll
    for (int tt = 0; tt < 2; ++tt) {
        int t = w * 2 + tt;                    // wave w handles t = 2w, 2w+1
        f32x4 acch = {0.f, 0.f, 0.f, 0.f};
        f32x4 accu = {0.f, 0.f, 0.f, 0.f};
        const unsigned short* wwrow = WwB + (t * 16 + c) * 128;
        const unsigned short* w2row = W2T + (t * 16 + c) * 128;
#pragma unroll
        for (int ks = 0; ks < 4; ++ks) {
            bf16x8 bw = *reinterpret_cast<const bf16x8*>(wwrow + ks * 32 + q * 8);
            bf16x8 b2 = *reinterpret_cast<const bf16x8*>(w2row + ks * 32 + q * 8);
            acch = __builtin_amdgcn_mfma_f32_16x16x32_bf16(xa[ks], bw, acch, 0, 0, 0);
            accu = __builtin_amdgcn_mfma_f32_16x16x32_bf16(xa[ks], b2, accu, 0, 0, 0);
        }
        float wb = Wb[t * 16 + c];
        float ub = wbA[t * 16 + c];
#pragma unroll
        for (int r = 0; r < 4; ++r) {
            int row = rowbase + q * 4 + r;
            unsigned short hv = f2b(acch[r] + wb);
            unsigned short uv = f2b(accu[r] + ub);
            h[(size_t)row * 128 + t * 16 + c] = hv;
            u[(size_t)row * 128 + t * 16 + c] = uv;
            lds[q * 4 + r][t * 16 + c] = hv;
        }
    }
    __syncthreads();
    int tid = threadIdx.x;
    if (tid < 128) {                           // thread tid transposes feature d=tid
        int d = tid;
        unsigned int p[8];
#pragma unroll
        for (int k = 0; k < 8; ++k) {
            unsigned int v0 = lds[2 * k][d], v1 = lds[2 * k + 1][d];
            p[k] = v0 | (v1 << 16);
        }
        size_t basehT = ((size_t)(b * 128 + d)) * 1024 + n0;
        uint4* dst = reinterpret_cast<uint4*>(hT + basehT);
        dst[0] = make_uint4(p[0], p[1], p[2], p[3]);
        dst[1] = make_uint4(p[4], p[5], p[6], p[7]);
    }
}

// ---------------- K2: column sums (grid 1024, 16 cols/block) ----------------
__global__ __launch_bounds__(256) void k2_stats(
    const unsigned short* __restrict__ h, const unsigned short* __restrict__ u,
    const unsigned long long* __restrict__ maskJ, float* __restrict__ rl0) {
    int w = threadIdx.x >> 6, lane = threadIdx.x & 63;
    int c = lane & 15, q = lane >> 4;
    int b = blockIdx.x >> 6;
    int j0 = (blockIdx.x & 63) * 16;
    const unsigned short* hb = h + (size_t)b * N_ * D_;
    const unsigned short* ub = u + (size_t)b * N_ * D_;

    bf16x8 Bh[4], Bu[4];
#pragma unroll
    for (int ks = 0; ks < 4; ++ks) {
        Bh[ks] = *reinterpret_cast<const bf16x8*>(hb + (j0 + c) * 128 + ks * 32 + q * 8);
        Bu[ks] = *reinterpret_cast<const bf16x8*>(ub + (j0 + c) * 128 + ks * 32 + q * 8);
    }
    float colsum = 0.f;
    const unsigned long long* mrow = maskJ + (size_t)b * 1024 * 16 + (j0 >> 6);
    int jb = j0 & 63;

    for (int it = w; it < 64; it += 4) {       // wave w covers 16 i-tiles
        int i0 = it * 16;
        f32x4 acc = {0.f, 0.f, 0.f, 0.f};
#pragma unroll
        for (int ks = 0; ks < 4; ++ks) {
            bf16x8 au = *reinterpret_cast<const bf16x8*>(ub + (i0 + c) * 128 + ks * 32 + q * 8);
            bf16x8 ah = *reinterpret_cast<const bf16x8*>(hb + (i0 + c) * 128 + ks * 32 + q * 8);
            acc = __builtin_amdgcn_mfma_f32_16x16x32_bf16(au, Bh[ks], acc, 0, 0, 0);
            acc = __builtin_amdgcn_mfma_f32_16x16x32_bf16(ah, Bu[ks], acc, 0, 0, 0);
        }
#pragma unroll
        for (int r = 0; r < 4; ++r) {
            int i = i0 + q * 4 + r;
            unsigned long long mword = mrow[(size_t)i * 16];
            bool m = (mword >> (jb + c)) & 1ull;
            colsum += m ? __expf(clamp60(acc[r])) : 1.0f;
        }
    }
    colsum += __shfl_xor(colsum, 16, 64);
    colsum += __shfl_xor(colsum, 32, 64);
    __shared__ float part[4][16];
    if (lane < 16) part[w][lane] = colsum;
    __syncthreads();
    if (threadIdx.x < 16) {
        float s = part[0][threadIdx.x] + part[1][threadIdx.x]
                + part[2][threadIdx.x] + part[3][threadIdx.x];
        rl0[b * 1024 + j0 + threadIdx.x] = 1.0f / s;
    }
}

// ---------------- K3: fused scores + aggregation + gates ----------------
__global__ __launch_bounds__(256) void k3_fused(
    const unsigned short* __restrict__ h, const unsigned short* __restrict__ uu,
    const unsigned long long* __restrict__ maskJ, const float* __restrict__ rl0,
    const unsigned short* __restrict__ hT, const float* __restrict__ x,
    const float* __restrict__ wi_u, const float* __restrict__ wi_x,
    const float* __restrict__ wf_u, const float* __restrict__ wf_x,
    const float* __restrict__ wo_u, const float* __restrict__ wo_x,
    float* __restrict__ out) {
    __shared__ float red[4][16][129];          // hp partials (+1 pad)
    int w = threadIdx.x >> 6, lane = threadIdx.x & 63;
    int c = lane & 15, q = lane >> 4;
    int b = blockIdx.x >> 6;
    int i0 = (blockIdx.x & 63) * 16;           // this block's 16 output rows
    const unsigned short* hb = h + (size_t)b * N_ * D_;
    const unsigned short* ub = uu + (size_t)b * N_ * D_;
    const unsigned short* hTb = hT + (size_t)b * 128 * 1024;
    const unsigned long long* mrowI = maskJ + (size_t)(b * 1024 + i0 + c) * 16;
    const float* rl0b = rl0 + b * 1024;

    // score B-fragments: fixed i-side (columns of e^T); lane c <-> row i0+c
    bf16x8 Bh[4], Bu[4];
#pragma unroll
    for (int ks = 0; ks < 4; ++ks) {
        Bh[ks] = *reinterpret_cast<const bf16x8*>(hb + (i0 + c) * 128 + ks * 32 + q * 8);
        Bu[ks] = *reinterpret_cast<const bf16x8*>(ub + (i0 + c) * 128 + ks * 32 + q * 8);
    }

    f32x4 hp[8];
#pragma unroll
    for (int t = 0; t < 8; ++t) hp[t] = (f32x4){0.f, 0.f, 0.f, 0.f};

    for (int jp = w; jp < 32; jp += 4) {       // wave w covers 8 j-chunks of 32
        int j0 = jp * 32;
        unsigned long long mw64 = mrowI[jp >> 1];
        unsigned int mbits = (unsigned int)(mw64 >> ((jp & 1) * 32));
        unsigned int u00, u01, u10, u11;
#pragma unroll
        for (int s = 0; s < 2; ++s) {
            int js = j0 + s * 16;
            f32x4 acc = {0.f, 0.f, 0.f, 0.f};
#pragma unroll
            for (int ks = 0; ks < 4; ++ks) {
                bf16x8 au = *reinterpret_cast<const bf16x8*>(ub + (js + c) * 128 + ks * 32 + q * 8);
                bf16x8 ah = *reinterpret_cast<const bf16x8*>(hb + (js + c) * 128 + ks * 32 + q * 8);
                acc = __builtin_amdgcn_mfma_f32_16x16x32_bf16(au, Bh[ks], acc, 0, 0, 0);
                acc = __builtin_amdgcn_mfma_f32_16x16x32_bf16(ah, Bu[ks], acc, 0, 0, 0);
            }
            // e^T element: (j = js + q*4 + r, i = i0 + c)
            float4 rv = *reinterpret_cast<const float4*>(rl0b + js + q * 4);
            int bb = s * 16 + q * 4;
            float a0 = ((mbits >> (bb + 0)) & 1u) ? __expf(clamp60(acc[0])) * rv.x : 0.f;
            float a1 = ((mbits >> (bb + 1)) & 1u) ? __expf(clamp60(acc[1])) * rv.y : 0.f;
            float a2 = ((mbits >> (bb + 2)) & 1u) ? __expf(clamp60(acc[2])) * rv.z : 0.f;
            float a3 = ((mbits >> (bb + 3)) & 1u) ? __expf(clamp60(acc[3])) * rv.w : 0.f;
            unsigned int p0 = (unsigned int)f2b(a0) | ((unsigned int)f2b(a1) << 16);
            unsigned int p1 = (unsigned int)f2b(a2) | ((unsigned int)f2b(a3) << 16);
            if (s == 0) { u00 = p0; u01 = p1; } else { u10 = p0; u11 = p1; }
        }
        // shfl-transpose C-layout -> A-layout (lane q needs j = q*8..q*8+7)
        int la = c + 32 * (q & 1);
        int lb = la + 16;
        unsigned int x0 = __shfl((int)u00, la, 64), x1 = __shfl((int)u01, la, 64);
        unsigned int x2 = __shfl((int)u00, lb, 64), x3 = __shfl((int)u01, lb, 64);
        unsigned int y0 = __shfl((int)u10, la, 64), y1 = __shfl((int)u11, la, 64);
        unsigned int y2 = __shfl((int)u10, lb, 64), y3 = __shfl((int)u11, lb, 64);
        bool hiq = (q >> 1) != 0;
        union { unsigned int ui[4]; bf16x8 v; } att;
        att.ui[0] = hiq ? y0 : x0;
        att.ui[1] = hiq ? y1 : x1;
        att.ui[2] = hiq ? y2 : x2;
        att.ui[3] = hiq ? y3 : x3;
#pragma unroll
        for (int t = 0; t < 8; ++t) {
            bf16x8 bt = *reinterpret_cast<const bf16x8*>(
                hTb + (size_t)(t * 16 + c) * 1024 + j0 + q * 8);
            hp[t] = __builtin_amdgcn_mfma_f32_16x16x32_bf16(att.v, bt, hp[t], 0, 0, 0);
        }
    }

    // cross-wave reduce of hp, then epilogue by wave 0
#pragma unroll
    for (int t = 0; t < 8; ++t)
#pragma unroll
        for (int r = 0; r < 4; ++r)
            red[w][q * 4 + r][t * 16 + c] = hp[t][r];
    __syncthreads();
    if (w != 0) return;

#pragma unroll
    for (int t = 0; t < 8; ++t)
#pragma unroll
        for (int r = 0; r < 4; ++r)
            hp[t][r] = red[0][q * 4 + r][t * 16 + c] + red[1][q * 4 + r][t * 16 + c]
                     + red[2][q * 4 + r][t * 16 + c] + red[3][q * 4 + r][t * 16 + c];

    float xv[8][4];
#pragma unroll
    for (int t = 0; t < 8; ++t)
#pragma unroll
        for (int r = 0; r < 4; ++r) {
            hp[t][r] = fmaxf(hp[t][r], 0.f);
            xv[t][r] = x[(size_t)(b * 1024 + i0 + q * 4 + r) * 128 + t * 16 + c];
        }
    float wiu[8], wix[8], wfu[8], wfx[8], wou[8], wox[8];
#pragma unroll
    for (int t = 0; t < 8; ++t) {
        wiu[t] = wi_u[t * 16 + c]; wix[t] = wi_x[t * 16 + c];
        wfu[t] = wf_u[t * 16 + c]; wfx[t] = wf_x[t * 16 + c];
        wou[t] = wo_u[t * 16 + c]; wox[t] = wo_x[t * 16 + c];
    }
#pragma unroll
    for (int r = 0; r < 4; ++r) {
        float zi = 0.f, zf = 0.f, zo = 0.f;
#pragma unroll
        for (int t = 0; t < 8; ++t) {
            zi += hp[t][r] * wiu[t] + xv[t][r] * wix[t];
            zf += hp[t][r] * wfu[t] + xv[t][r] * wfx[t];
            zo += hp[t][r] * wou[t] + xv[t][r] * wox[t];
        }
        zi += __shfl_xor(zi, 1, 64); zi += __shfl_xor(zi, 2, 64);
        zi += __shfl_xor(zi, 4, 64); zi += __shfl_xor(zi, 8, 64);
        zf += __shfl_xor(zf, 1, 64); zf += __shfl_xor(zf, 2, 64);
        zf += __shfl_xor(zf, 4, 64); zf += __shfl_xor(zf, 8, 64);
        zo += __shfl_xor(zo, 1, 64); zo += __shfl_xor(zo, 2, 64);
        zo += __shfl_xor(zo, 4, 64); zo += __shfl_xor(zo, 8, 64);
        float ic = 1.f / (1.f + __expf(-zi));
        float fc = 1.f / (1.f + __expf(-zf));
        float oc = 1.f / (1.f + __expf(-zo));
#pragma unroll
        for (int t = 0; t < 8; ++t) {
            float zz = ic * hp[t][r] + fc * xv[t][r];
            float th = 1.f - 2.f / (__expf(2.f * zz) + 1.f);
            out[(size_t)(b * 1024 + i0 + q * 4 + r) * 128 + t * 16 + c] = oc * th;
        }
    }
}

extern "C" void kernel_launch(void* const* d_in, const int* in_sizes, int n_in,
                              void* d_out, int out_size, void* d_ws, size_t ws_size,
                              hipStream_t stream) {
    const float* x    = (const float*)d_in[0];
    const float* adj  = (const float*)d_in[1];
    const float* Ww   = (const float*)d_in[2];
    const float* Wb   = (const float*)d_in[3];
    const float* A    = (const float*)d_in[4];
    const float* wi_u = (const float*)d_in[5];
    const float* wi_x = (const float*)d_in[6];
    const float* wf_u = (const float*)d_in[7];
    const float* wf_x = (const float*)d_in[8];
    const float* wo_u = (const float*)d_in[9];
    const float* wo_x = (const float*)d_in[10];
    float* out = (float*)d_out;

    char* ws = (char*)d_ws;
    unsigned short* WwB = (unsigned short*)(ws);                          // 32KB
    unsigned short* W2T = (unsigned short*)(ws + (32u << 10));            // 32KB
    float* wbA          = (float*)(ws + (64u << 10));                     // 512B
    float* rl0          = (float*)(ws + (128u << 10));                    // 64KB
    unsigned short* h   = (unsigned short*)(ws + (1u << 20));             // 4MB
    unsigned short* u   = (unsigned short*)(ws + (5u << 20));             // 4MB
    unsigned short* hT  = (unsigned short*)(ws + (9u << 20));             // 4MB
    unsigned long long* maskJ = (unsigned long long*)(ws + (13u << 20));  // 2MB

    k0_w2t<<<64, 256, 0, stream>>>(Ww, Wb, A, WwB, W2T, wbA);
    kmask<<<16384, 256, 0, stream>>>(adj, maskJ);
    k1_hu<<<1024, 256, 0, stream>>>(x, WwB, Wb, W2T, wbA, h, u, hT);
    k2_stats<<<1024, 256, 0, stream>>>(h, u, maskJ, rl0);
    k3_fused<<<1024, 256, 0, stream>>>(h, u, maskJ, rl0, hT, x,
                                       wi_u, wi_x, wf_u, wf_x, wo_u, wo_x, out);
}

// Round 5
// 253.322 us; speedup vs baseline: 1.7213x; 1.2489x over previous
//
#include <hip/hip_runtime.h>

// GAT_gate: B=16, N=1024, D=128. FP32 I/O; bf16 MFMA internally, fp32 accum.
//
// Fast path (ws >= 84MB):
//  K0:    WwB = bf16(Ww); W2T = bf16(A^T Ww); wbA = Wb@A (fp32)
//  kmask: adj (64MB fp32) -> 2MB bitmask packed along j
//  K1:    h = x@Ww^T+Wb ; u = x@W2T^T+wbA -> h,u bf16; hT bf16 [b][d][n]
//  K2s:   block = 16 rows i. A-frags hoisted; stream j-tiles (dbuf B-frags,
//         2 indep MFMA chains). esc = mask?exp(e):0 -> att fp32 (64MB);
//         partial colsums -> colpart (deterministic, no atomics).
//  K2b:   rl0[j] = 1 / sum_iblk colpart
//  K3g:   pure GEMM h' = relu((att*rl0[j]) @ h) vs hT + LSTM-gate epilogue.
// Fallback path (ws < 84MB): round-4 kernels (k2_stats + k3_fused).

#define B_ 16
#define N_ 1024
#define D_ 128

typedef __attribute__((ext_vector_type(8))) short bf16x8;
typedef __attribute__((ext_vector_type(4))) float f32x4;

__device__ __forceinline__ unsigned short f2b(float f) {
    union { float f; unsigned int i; } v; v.f = f;
    unsigned int x = v.i;
    return (unsigned short)((x + 0x7fffu + ((x >> 16) & 1u)) >> 16);
}
__device__ __forceinline__ float clamp60(float v) {
    return fminf(fmaxf(v, -60.f), 60.f);
}
__device__ __forceinline__ bf16x8 load8f(const float* p) {
    float4 a = *reinterpret_cast<const float4*>(p);
    float4 b = *reinterpret_cast<const float4*>(p + 4);
    bf16x8 v;
    v[0] = (short)f2b(a.x); v[1] = (short)f2b(a.y);
    v[2] = (short)f2b(a.z); v[3] = (short)f2b(a.w);
    v[4] = (short)f2b(b.x); v[5] = (short)f2b(b.y);
    v[6] = (short)f2b(b.z); v[7] = (short)f2b(b.w);
    return v;
}

// ---------------- K0: fold weights ----------------
__global__ __launch_bounds__(256) void k0_w2t(
    const float* __restrict__ Ww, const float* __restrict__ Wb,
    const float* __restrict__ A, unsigned short* __restrict__ WwB,
    unsigned short* __restrict__ W2T, float* __restrict__ wbA) {
    int t = blockIdx.x * 256 + threadIdx.x;
    int l = t >> 7, f = t & 127;
    float acc = 0.f;
    for (int d = 0; d < 128; ++d)
        acc += A[d * 128 + l] * Ww[d * 128 + f];
    W2T[l * 128 + f] = f2b(acc);
    WwB[t] = f2b(Ww[t]);
    if (blockIdx.x == 0 && threadIdx.x < 128) {
        float s = 0.f;
        for (int d = 0; d < 128; ++d) s += Wb[d] * A[d * 128 + threadIdx.x];
        wbA[threadIdx.x] = s;
    }
}

// ---------------- kmask: adj -> bitmask ----------------
__global__ __launch_bounds__(256) void kmask(
    const float* __restrict__ adj, unsigned long long* __restrict__ maskJ) {
    int w = threadIdx.x >> 6, lane = threadIdx.x & 63;
    size_t base = ((size_t)blockIdx.x * 4 + w) * 256;
    unsigned long long w0 = __ballot(adj[base + 0 * 64 + lane] > 0.f);
    unsigned long long w1 = __ballot(adj[base + 1 * 64 + lane] > 0.f);
    unsigned long long w2 = __ballot(adj[base + 2 * 64 + lane] > 0.f);
    unsigned long long w3 = __ballot(adj[base + 3 * 64 + lane] > 0.f);
    unsigned long long o = lane == 0 ? w0 : lane == 1 ? w1 : lane == 2 ? w2 : w3;
    if (lane < 4) maskJ[(base >> 6) + lane] = o;
}

// ---------------- K1: h, u, hT ----------------
__global__ __launch_bounds__(256) void k1_hu(
    const float* __restrict__ x, const unsigned short* __restrict__ WwB,
    const float* __restrict__ Wb, const unsigned short* __restrict__ W2T,
    const float* __restrict__ wbA,
    unsigned short* __restrict__ h, unsigned short* __restrict__ u,
    unsigned short* __restrict__ hT) {
    __shared__ unsigned short lds[16][128];
    int w = threadIdx.x >> 6, lane = threadIdx.x & 63;
    int c = lane & 15, q = lane >> 4;
    int rowbase = blockIdx.x * 16;
    int b = rowbase >> 10;
    int n0 = rowbase & 1023;

    bf16x8 xa[4];
    const float* xrow = x + (size_t)(rowbase + c) * 128;
#pragma unroll
    for (int ks = 0; ks < 4; ++ks)
        xa[ks] = load8f(xrow + ks * 32 + q * 8);

#pragma unroll
    for (int tt = 0; tt < 2; ++tt) {
        int t = w * 2 + tt;
        f32x4 acch = {0.f, 0.f, 0.f, 0.f};
        f32x4 accu = {0.f, 0.f, 0.f, 0.f};
        const unsigned short* wwrow = WwB + (t * 16 + c) * 128;
        const unsigned short* w2row = W2T + (t * 16 + c) * 128;
#pragma unroll
        for (int ks = 0; ks < 4; ++ks) {
            bf16x8 bw = *reinterpret_cast<const bf16x8*>(wwrow + ks * 32 + q * 8);
            bf16x8 b2 = *reinterpret_cast<const bf16x8*>(w2row + ks * 32 + q * 8);
            acch = __builtin_amdgcn_mfma_f32_16x16x32_bf16(xa[ks], bw, acch, 0, 0, 0);
            accu = __builtin_amdgcn_mfma_f32_16x16x32_bf16(xa[ks], b2, accu, 0, 0, 0);
        }
        float wb = Wb[t * 16 + c];
        float ub = wbA[t * 16 + c];
#pragma unroll
        for (int r = 0; r < 4; ++r) {
            int row = rowbase + q * 4 + r;
            unsigned short hv = f2b(acch[r] + wb);
            unsigned short uv = f2b(accu[r] + ub);
            h[(size_t)row * 128 + t * 16 + c] = hv;
            u[(size_t)row * 128 + t * 16 + c] = uv;
            lds[q * 4 + r][t * 16 + c] = hv;
        }
    }
    __syncthreads();
    int tid = threadIdx.x;
    if (tid < 128) {
        int d = tid;
        unsigned int p[8];
#pragma unroll
        for (int k = 0; k < 8; ++k) {
            unsigned int v0 = lds[2 * k][d], v1 = lds[2 * k + 1][d];
            p[k] = v0 | (v1 << 16);
        }
        size_t basehT = ((size_t)(b * 128 + d)) * 1024 + n0;
        uint4* dst = reinterpret_cast<uint4*>(hT + basehT);
        dst[0] = make_uint4(p[0], p[1], p[2], p[3]);
        dst[1] = make_uint4(p[4], p[5], p[6], p[7]);
    }
}

// ========== FAST PATH ==========

// K2s: block = 16 rows i; stream all j; esc fp32 + partial colsums.
__global__ __launch_bounds__(256) void k2_scores(
    const unsigned short* __restrict__ h, const unsigned short* __restrict__ u,
    const unsigned long long* __restrict__ maskJ,
    float* __restrict__ att, float* __restrict__ colpart) {
    __shared__ unsigned long long lmask[16][16];
    int w = threadIdx.x >> 6, lane = threadIdx.x & 63;
    int c = lane & 15, q = lane >> 4;
    int b = blockIdx.x >> 6;
    int iblk = blockIdx.x & 63;
    int i0 = iblk * 16;
    const unsigned short* hb = h + (size_t)b * N_ * D_;
    const unsigned short* ub = u + (size_t)b * N_ * D_;

    lmask[threadIdx.x >> 4][threadIdx.x & 15] =
        maskJ[(size_t)(b * 1024 + i0 + (threadIdx.x >> 4)) * 16 + (threadIdx.x & 15)];
    __syncthreads();

    bf16x8 Au[4], Ah[4];
#pragma unroll
    for (int ks = 0; ks < 4; ++ks) {
        Au[ks] = *reinterpret_cast<const bf16x8*>(ub + (i0 + c) * 128 + ks * 32 + q * 8);
        Ah[ks] = *reinterpret_cast<const bf16x8*>(hb + (i0 + c) * 128 + ks * 32 + q * 8);
    }
    float* attrow = att + ((size_t)(b * 1024 + i0)) * 1024;
    float* cprow = colpart + ((size_t)(b * 64 + iblk)) * 1024;

    int jt0 = w * 16;                         // wave w: tiles jt0..jt0+15
    bf16x8 Bh[2][4], Bu[2][4];
#pragma unroll
    for (int ks = 0; ks < 4; ++ks) {
        Bh[0][ks] = *reinterpret_cast<const bf16x8*>(hb + (jt0 * 16 + c) * 128 + ks * 32 + q * 8);
        Bu[0][ks] = *reinterpret_cast<const bf16x8*>(ub + (jt0 * 16 + c) * 128 + ks * 32 + q * 8);
    }
#pragma unroll
    for (int t = 0; t < 16; ++t) {
        int jt = jt0 + t, j0 = jt * 16;
        int cur = t & 1, nxt = cur ^ 1;
        if (t < 15) {
            int jn = (jt + 1) * 16;
#pragma unroll
            for (int ks = 0; ks < 4; ++ks) {
                Bh[nxt][ks] = *reinterpret_cast<const bf16x8*>(hb + (jn + c) * 128 + ks * 32 + q * 8);
                Bu[nxt][ks] = *reinterpret_cast<const bf16x8*>(ub + (jn + c) * 128 + ks * 32 + q * 8);
            }
        }
        f32x4 a1 = {0.f, 0.f, 0.f, 0.f};
        f32x4 a2 = {0.f, 0.f, 0.f, 0.f};
#pragma unroll
        for (int ks = 0; ks < 4; ++ks) {
            a1 = __builtin_amdgcn_mfma_f32_16x16x32_bf16(Au[ks], Bh[cur][ks], a1, 0, 0, 0);
            a2 = __builtin_amdgcn_mfma_f32_16x16x32_bf16(Ah[ks], Bu[cur][ks], a2, 0, 0, 0);
        }
        int wd = jt >> 2, sh = (jt & 3) * 16;
        float colp = 0.f;
#pragma unroll
        for (int r = 0; r < 4; ++r) {
            float e = a1[r] + a2[r];            // e[i0+q*4+r][j0+c]
            bool m = (lmask[q * 4 + r][wd] >> (sh + c)) & 1ull;
            float ex = m ? __expf(clamp60(e)) : 0.f;
            colp += m ? ex : 1.0f;
            attrow[(size_t)(q * 4 + r) * 1024 + j0 + c] = ex;
        }
        colp += __shfl_xor(colp, 16, 64);
        colp += __shfl_xor(colp, 32, 64);
        if (q == 0) cprow[j0 + c] = colp;
    }
}

// K2b: rl0 = 1/sum(colpart)
__global__ __launch_bounds__(256) void k2b_recip(
    const float* __restrict__ colpart, float* __restrict__ rl0) {
    int g = blockIdx.x * 256 + threadIdx.x;   // 0..16383
    int b = g >> 10, j = g & 1023;
    float s = 0.f;
    const float* p = colpart + (size_t)b * 64 * 1024 + j;
    for (int ib = 0; ib < 64; ++ib) s += p[(size_t)ib * 1024];
    rl0[g] = 1.0f / s;
}

// K3g: pure GEMM h' = relu((att*rl0) @ h) + gates
__global__ __launch_bounds__(256) void k3_gemm(
    const float* __restrict__ att, const float* __restrict__ rl0,
    const unsigned short* __restrict__ hT, const float* __restrict__ x,
    const float* __restrict__ wi_u, const float* __restrict__ wi_x,
    const float* __restrict__ wf_u, const float* __restrict__ wf_x,
    const float* __restrict__ wo_u, const float* __restrict__ wo_x,
    float* __restrict__ out) {
    __shared__ float red[4][16][129];
    int w = threadIdx.x >> 6, lane = threadIdx.x & 63;
    int c = lane & 15, q = lane >> 4;
    int b = blockIdx.x >> 6;
    int i0 = (blockIdx.x & 63) * 16;
    const float* attrow = att + ((size_t)(b * 1024 + i0 + c)) * 1024;
    const unsigned short* hTb = hT + (size_t)b * 128 * 1024;
    const float* rl0b = rl0 + b * 1024;

    f32x4 hp[8];
#pragma unroll
    for (int t = 0; t < 8; ++t) hp[t] = (f32x4){0.f, 0.f, 0.f, 0.f};

#pragma unroll
    for (int tt = 0; tt < 8; ++tt) {
        int jp = w * 8 + tt;                  // wave w: chunks w*8..w*8+7
        int jb = jp * 32 + q * 8;
        float4 e0 = *reinterpret_cast<const float4*>(attrow + jb);
        float4 e1 = *reinterpret_cast<const float4*>(attrow + jb + 4);
        float4 r0 = *reinterpret_cast<const float4*>(rl0b + jb);
        float4 r1 = *reinterpret_cast<const float4*>(rl0b + jb + 4);
        bf16x8 a;
        a[0] = (short)f2b(e0.x * r0.x); a[1] = (short)f2b(e0.y * r0.y);
        a[2] = (short)f2b(e0.z * r0.z); a[3] = (short)f2b(e0.w * r0.w);
        a[4] = (short)f2b(e1.x * r1.x); a[5] = (short)f2b(e1.y * r1.y);
        a[6] = (short)f2b(e1.z * r1.z); a[7] = (short)f2b(e1.w * r1.w);
#pragma unroll
        for (int t = 0; t < 8; ++t) {
            bf16x8 bt = *reinterpret_cast<const bf16x8*>(
                hTb + (size_t)(t * 16 + c) * 1024 + jp * 32 + q * 8);
            hp[t] = __builtin_amdgcn_mfma_f32_16x16x32_bf16(a, bt, hp[t], 0, 0, 0);
        }
    }

#pragma unroll
    for (int t = 0; t < 8; ++t)
#pragma unroll
        for (int r = 0; r < 4; ++r)
            red[w][q * 4 + r][t * 16 + c] = hp[t][r];
    __syncthreads();
    if (w != 0) return;

#pragma unroll
    for (int t = 0; t < 8; ++t)
#pragma unroll
        for (int r = 0; r < 4; ++r)
            hp[t][r] = red[0][q * 4 + r][t * 16 + c] + red[1][q * 4 + r][t * 16 + c]
                     + red[2][q * 4 + r][t * 16 + c] + red[3][q * 4 + r][t * 16 + c];

    float xv[8][4];
#pragma unroll
    for (int t = 0; t < 8; ++t)
#pragma unroll
        for (int r = 0; r < 4; ++r) {
            hp[t][r] = fmaxf(hp[t][r], 0.f);
            xv[t][r] = x[(size_t)(b * 1024 + i0 + q * 4 + r) * 128 + t * 16 + c];
        }
    float wiu[8], wix[8], wfu[8], wfx[8], wou[8], wox[8];
#pragma unroll
    for (int t = 0; t < 8; ++t) {
        wiu[t] = wi_u[t * 16 + c]; wix[t] = wi_x[t * 16 + c];
        wfu[t] = wf_u[t * 16 + c]; wfx[t] = wf_x[t * 16 + c];
        wou[t] = wo_u[t * 16 + c]; wox[t] = wo_x[t * 16 + c];
    }
#pragma unroll
    for (int r = 0; r < 4; ++r) {
        float zi = 0.f, zf = 0.f, zo = 0.f;
#pragma unroll
        for (int t = 0; t < 8; ++t) {
            zi += hp[t][r] * wiu[t] + xv[t][r] * wix[t];
            zf += hp[t][r] * wfu[t] + xv[t][r] * wfx[t];
            zo += hp[t][r] * wou[t] + xv[t][r] * wox[t];
        }
        zi += __shfl_xor(zi, 1, 64); zi += __shfl_xor(zi, 2, 64);
        zi += __shfl_xor(zi, 4, 64); zi += __shfl_xor(zi, 8, 64);
        zf += __shfl_xor(zf, 1, 64); zf += __shfl_xor(zf, 2, 64);
        zf += __shfl_xor(zf, 4, 64); zf += __shfl_xor(zf, 8, 64);
        zo += __shfl_xor(zo, 1, 64); zo += __shfl_xor(zo, 2, 64);
        zo += __shfl_xor(zo, 4, 64); zo += __shfl_xor(zo, 8, 64);
        float ic = 1.f / (1.f + __expf(-zi));
        float fc = 1.f / (1.f + __expf(-zf));
        float oc = 1.f / (1.f + __expf(-zo));
#pragma unroll
        for (int t = 0; t < 8; ++t) {
            float zz = ic * hp[t][r] + fc * xv[t][r];
            float th = 1.f - 2.f / (__expf(2.f * zz) + 1.f);
            out[(size_t)(b * 1024 + i0 + q * 4 + r) * 128 + t * 16 + c] = oc * th;
        }
    }
}

// ========== FALLBACK PATH (round-4, proven) ==========
__global__ __launch_bounds__(256) void k2_stats(
    const unsigned short* __restrict__ h, const unsigned short* __restrict__ u,
    const unsigned long long* __restrict__ maskJ, float* __restrict__ rl0) {
    int w = threadIdx.x >> 6, lane = threadIdx.x & 63;
    int c = lane & 15, q = lane >> 4;
    int b = blockIdx.x >> 6;
    int j0 = (blockIdx.x & 63) * 16;
    const unsigned short* hb = h + (size_t)b * N_ * D_;
    const unsigned short* ub = u + (size_t)b * N_ * D_;

    bf16x8 Bh[4], Bu[4];
#pragma unroll
    for (int ks = 0; ks < 4; ++ks) {
        Bh[ks] = *reinterpret_cast<const bf16x8*>(hb + (j0 + c) * 128 + ks * 32 + q * 8);
        Bu[ks] = *reinterpret_cast<const bf16x8*>(ub + (j0 + c) * 128 + ks * 32 + q * 8);
    }
    float colsum = 0.f;
    const unsigned long long* mrow = maskJ + (size_t)b * 1024 * 16 + (j0 >> 6);
    int jb = j0 & 63;

    for (int it = w; it < 64; it += 4) {
        int i0 = it * 16;
        f32x4 acc = {0.f, 0.f, 0.f, 0.f};
#pragma unroll
        for (int ks = 0; ks < 4; ++ks) {
            bf16x8 au = *reinterpret_cast<const bf16x8*>(ub + (i0 + c) * 128 + ks * 32 + q * 8);
            bf16x8 ah = *reinterpret_cast<const bf16x8*>(hb + (i0 + c) * 128 + ks * 32 + q * 8);
            acc = __builtin_amdgcn_mfma_f32_16x16x32_bf16(au, Bh[ks], acc, 0, 0, 0);
            acc = __builtin_amdgcn_mfma_f32_16x16x32_bf16(ah, Bu[ks], acc, 0, 0, 0);
        }
#pragma unroll
        for (int r = 0; r < 4; ++r) {
            int i = i0 + q * 4 + r;
            unsigned long long mword = mrow[(size_t)i * 16];
            bool m = (mword >> (jb + c)) & 1ull;
            colsum += m ? __expf(clamp60(acc[r])) : 1.0f;
        }
    }
    colsum += __shfl_xor(colsum, 16, 64);
    colsum += __shfl_xor(colsum, 32, 64);
    __shared__ float part[4][16];
    if (lane < 16) part[w][lane] = colsum;
    __syncthreads();
    if (threadIdx.x < 16) {
        float s = part[0][threadIdx.x] + part[1][threadIdx.x]
                + part[2][threadIdx.x] + part[3][threadIdx.x];
        rl0[b * 1024 + j0 + threadIdx.x] = 1.0f / s;
    }
}

__global__ __launch_bounds__(256) void k3_fused(
    const unsigned short* __restrict__ h, const unsigned short* __restrict__ uu,
    const unsigned long long* __restrict__ maskJ, const float* __restrict__ rl0,
    const unsigned short* __restrict__ hT, const float* __restrict__ x,
    const float* __restrict__ wi_u, const float* __restrict__ wi_x,
    const float* __restrict__ wf_u, const float* __restrict__ wf_x,
    const float* __restrict__ wo_u, const float* __restrict__ wo_x,
    float* __restrict__ out) {
    __shared__ float red[4][16][129];
    int w = threadIdx.x >> 6, lane = threadIdx.x & 63;
    int c = lane & 15, q = lane >> 4;
    int b = blockIdx.x >> 6;
    int i0 = (blockIdx.x & 63) * 16;
    const unsigned short* hb = h + (size_t)b * N_ * D_;
    const unsigned short* ub = uu + (size_t)b * N_ * D_;
    const unsigned short* hTb = hT + (size_t)b * 128 * 1024;
    const unsigned long long* mrowI = maskJ + (size_t)(b * 1024 + i0 + c) * 16;
    const float* rl0b = rl0 + b * 1024;

    bf16x8 Bh[4], Bu[4];
#pragma unroll
    for (int ks = 0; ks < 4; ++ks) {
        Bh[ks] = *reinterpret_cast<const bf16x8*>(hb + (i0 + c) * 128 + ks * 32 + q * 8);
        Bu[ks] = *reinterpret_cast<const bf16x8*>(ub + (i0 + c) * 128 + ks * 32 + q * 8);
    }
    f32x4 hp[8];
#pragma unroll
    for (int t = 0; t < 8; ++t) hp[t] = (f32x4){0.f, 0.f, 0.f, 0.f};

    for (int jp = w; jp < 32; jp += 4) {
        int j0 = jp * 32;
        unsigned long long mw64 = mrowI[jp >> 1];
        unsigned int mbits = (unsigned int)(mw64 >> ((jp & 1) * 32));
        unsigned int u00, u01, u10, u11;
#pragma unroll
        for (int s = 0; s < 2; ++s) {
            int js = j0 + s * 16;
            f32x4 acc = {0.f, 0.f, 0.f, 0.f};
#pragma unroll
            for (int ks = 0; ks < 4; ++ks) {
                bf16x8 au = *reinterpret_cast<const bf16x8*>(ub + (js + c) * 128 + ks * 32 + q * 8);
                bf16x8 ah = *reinterpret_cast<const bf16x8*>(hb + (js + c) * 128 + ks * 32 + q * 8);
                acc = __builtin_amdgcn_mfma_f32_16x16x32_bf16(au, Bh[ks], acc, 0, 0, 0);
                acc = __builtin_amdgcn_mfma_f32_16x16x32_bf16(ah, Bu[ks], acc, 0, 0, 0);
            }
            float4 rv = *reinterpret_cast<const float4*>(rl0b + js + q * 4);
            int bb = s * 16 + q * 4;
            float a0 = ((mbits >> (bb + 0)) & 1u) ? __expf(clamp60(acc[0])) * rv.x : 0.f;
            float a1 = ((mbits >> (bb + 1)) & 1u) ? __expf(clamp60(acc[1])) * rv.y : 0.f;
            float a2 = ((mbits >> (bb + 2)) & 1u) ? __expf(clamp60(acc[2])) * rv.z : 0.f;
            float a3 = ((mbits >> (bb + 3)) & 1u) ? __expf(clamp60(acc[3])) * rv.w : 0.f;
            unsigned int p0 = (unsigned int)f2b(a0) | ((unsigned int)f2b(a1) << 16);
            unsigned int p1 = (unsigned int)f2b(a2) | ((unsigned int)f2b(a3) << 16);
            if (s == 0) { u00 = p0; u01 = p1; } else { u10 = p0; u11 = p1; }
        }
        int la = c + 32 * (q & 1);
        int lb = la + 16;
        unsigned int x0 = __shfl((int)u00, la, 64), x1 = __shfl((int)u01, la, 64);
        unsigned int x2 = __shfl((int)u00, lb, 64), x3 = __shfl((int)u01, lb, 64);
        unsigned int y0 = __shfl((int)u10, la, 64), y1 = __shfl((int)u11, la, 64);
        unsigned int y2 = __shfl((int)u10, lb, 64), y3 = __shfl((int)u11, lb, 64);
        bool hiq = (q >> 1) != 0;
        union { unsigned int ui[4]; bf16x8 v; } att;
        att.ui[0] = hiq ? y0 : x0;
        att.ui[1] = hiq ? y1 : x1;
        att.ui[2] = hiq ? y2 : x2;
        att.ui[3] = hiq ? y3 : x3;
#pragma unroll
        for (int t = 0; t < 8; ++t) {
            bf16x8 bt = *reinterpret_cast<const bf16x8*>(
                hTb + (size_t)(t * 16 + c) * 1024 + j0 + q * 8);
            hp[t] = __builtin_amdgcn_mfma_f32_16x16x32_bf16(att.v, bt, hp[t], 0, 0, 0);
        }
    }

#pragma unroll
    for (int t = 0; t < 8; ++t)
#pragma unroll
        for (int r = 0; r < 4; ++r)
            red[w][q * 4 + r][t * 16 + c] = hp[t][r];
    __syncthreads();
    if (w != 0) return;

#pragma unroll
    for (int t = 0; t < 8; ++t)
#pragma unroll
        for (int r = 0; r < 4; ++r)
            hp[t][r] = red[0][q * 4 + r][t * 16 + c] + red[1][q * 4 + r][t * 16 + c]
                     + red[2][q * 4 + r][t * 16 + c] + red[3][q * 4 + r][t * 16 + c];

    float xv[8][4];
#pragma unroll
    for (int t = 0; t < 8; ++t)
#pragma unroll
        for (int r = 0; r < 4; ++r) {
            hp[t][r] = fmaxf(hp[t][r], 0.f);
            xv[t][r] = x[(size_t)(b * 1024 + i0 + q * 4 + r) * 128 + t * 16 + c];
        }
    float wiu[8], wix[8], wfu[8], wfx[8], wou[8], wox[8];
#pragma unroll
    for (int t = 0; t < 8; ++t) {
        wiu[t] = wi_u[t * 16 + c]; wix[t] = wi_x[t * 16 + c];
        wfu[t] = wf_u[t * 16 + c]; wfx[t] = wf_x[t * 16 + c];
        wou[t] = wo_u[t * 16 + c]; wox[t] = wo_x[t * 16 + c];
    }
#pragma unroll
    for (int r = 0; r < 4; ++r) {
        float zi = 0.f, zf = 0.f, zo = 0.f;
#pragma unroll
        for (int t = 0; t < 8; ++t) {
            zi += hp[t][r] * wiu[t] + xv[t][r] * wix[t];
            zf += hp[t][r] * wfu[t] + xv[t][r] * wfx[t];
            zo += hp[t][r] * wou[t] + xv[t][r] * wox[t];
        }
        zi += __shfl_xor(zi, 1, 64); zi += __shfl_xor(zi, 2, 64);
        zi += __shfl_xor(zi, 4, 64); zi += __shfl_xor(zi, 8, 64);
        zf += __shfl_xor(zf, 1, 64); zf += __shfl_xor(zf, 2, 64);
        zf += __shfl_xor(zf, 4, 64); zf += __shfl_xor(zf, 8, 64);
        zo += __shfl_xor(zo, 1, 64); zo += __shfl_xor(zo, 2, 64);
        zo += __shfl_xor(zo, 4, 64); zo += __shfl_xor(zo, 8, 64);
        float ic = 1.f / (1.f + __expf(-zi));
        float fc = 1.f / (1.f + __expf(-zf));
        float oc = 1.f / (1.f + __expf(-zo));
#pragma unroll
        for (int t = 0; t < 8; ++t) {
            float zz = ic * hp[t][r] + fc * xv[t][r];
            float th = 1.f - 2.f / (__expf(2.f * zz) + 1.f);
            out[(size_t)(b * 1024 + i0 + q * 4 + r) * 128 + t * 16 + c] = oc * th;
        }
    }
}

extern "C" void kernel_launch(void* const* d_in, const int* in_sizes, int n_in,
                              void* d_out, int out_size, void* d_ws, size_t ws_size,
                              hipStream_t stream) {
    const float* x    = (const float*)d_in[0];
    const float* adj  = (const float*)d_in[1];
    const float* Ww   = (const float*)d_in[2];
    const float* Wb   = (const float*)d_in[3];
    const float* A    = (const float*)d_in[4];
    const float* wi_u = (const float*)d_in[5];
    const float* wi_x = (const float*)d_in[6];
    const float* wf_u = (const float*)d_in[7];
    const float* wf_x = (const float*)d_in[8];
    const float* wo_u = (const float*)d_in[9];
    const float* wo_x = (const float*)d_in[10];
    float* out = (float*)d_out;
    char* ws = (char*)d_ws;

    if (ws_size >= (84ull << 20)) {
        // fast path layout
        unsigned short* WwB = (unsigned short*)(ws);                      // 32K
        unsigned short* W2T = (unsigned short*)(ws + (32u << 10));        // 32K
        float* wbA          = (float*)(ws + (64u << 10));                 // 512B
        float* rl0          = (float*)(ws + (128u << 10));                // 64K
        unsigned long long* maskJ = (unsigned long long*)(ws + (256u << 10)); // 2M
        float* colpart      = (float*)(ws + (4ull << 20));                // 4M
        unsigned short* h   = (unsigned short*)(ws + (8ull << 20));       // 4M
        unsigned short* u   = (unsigned short*)(ws + (12ull << 20));      // 4M
        unsigned short* hT  = (unsigned short*)(ws + (16ull << 20));      // 4M
        float* att          = (float*)(ws + (20ull << 20));               // 64M

        k0_w2t<<<64, 256, 0, stream>>>(Ww, Wb, A, WwB, W2T, wbA);
        kmask<<<16384, 256, 0, stream>>>(adj, maskJ);
        k1_hu<<<1024, 256, 0, stream>>>(x, WwB, Wb, W2T, wbA, h, u, hT);
        k2_scores<<<1024, 256, 0, stream>>>(h, u, maskJ, att, colpart);
        k2b_recip<<<64, 256, 0, stream>>>(colpart, rl0);
        k3_gemm<<<1024, 256, 0, stream>>>(att, rl0, hT, x,
                                          wi_u, wi_x, wf_u, wf_x, wo_u, wo_x, out);
    } else {
        // fallback: round-4 layout + kernels
        unsigned short* WwB = (unsigned short*)(ws);
        unsigned short* W2T = (unsigned short*)(ws + (32u << 10));
        float* wbA          = (float*)(ws + (64u << 10));
        float* rl0          = (float*)(ws + (128u << 10));
        unsigned short* h   = (unsigned short*)(ws + (1u << 20));
        unsigned short* u   = (unsigned short*)(ws + (5u << 20));
        unsigned short* hT  = (unsigned short*)(ws + (9u << 20));
        unsigned long long* maskJ = (unsigned long long*)(ws + (13u << 20));

        k0_w2t<<<64, 256, 0, stream>>>(Ww, Wb, A, WwB, W2T, wbA);
        kmask<<<16384, 256, 0, stream>>>(adj, maskJ);
        k1_hu<<<1024, 256, 0, stream>>>(x, WwB, Wb, W2T, wbA, h, u, hT);
        k2_stats<<<1024, 256, 0, stream>>>(h, u, maskJ, rl0);
        k3_fused<<<1024, 256, 0, stream>>>(h, u, maskJ, rl0, hT, x,
                                           wi_u, wi_x, wf_u, wf_x, wo_u, wo_x, out);
    }
}